// Round 6
// baseline (245.867 us; speedup 1.0000x reference)
//
#include <hip/hip_runtime.h>

typedef _Float16 half8 __attribute__((ext_vector_type(8)));
typedef float f32x4 __attribute__((ext_vector_type(4)));

union Frag { half8 v; unsigned int u32[4]; uint4 u4; };
union Pack4 { _Float16 h[4]; uint2 u; };

constexpr int S = 4096;
constexpr int D = 64;
constexpr int NB = 16;
constexpr int LTS = 72;   // f16 LDS row stride (dword stride 36): min-phase b128 frag reads + b64 P writes

// ---- fused prepass: K f32 -> f16 row-major; V f32 -> f16 transposed [b][d][s] ----
__global__ __launch_bounds__(256)
void prep_kernel(const float* __restrict__ K, const float* __restrict__ V,
                 _Float16* __restrict__ K16, _Float16* __restrict__ VT) {
    __shared__ float tl[64 * 66];   // 66: 8B-aligned rows; col reads <=4-way (8 scalar reads only)
    const int tid = threadIdx.x;
    const int s0 = blockIdx.x * 64;
    const int b  = blockIdx.y;
    const float* Kb = K + ((size_t)b * S + s0) * D;
    const float* Vb = V + ((size_t)b * S + s0) * D;
    _Float16* K16b = K16 + ((size_t)b * S + s0) * D;

    #pragma unroll
    for (int i = 0; i < 2; ++i) {
        int e8 = tid + 256 * i;               // 8-float group within the 64x64 tile
        float4 a = ((const float4*)Kb)[2 * e8];
        float4 c = ((const float4*)Kb)[2 * e8 + 1];
        Frag f;
        f.v[0]=(_Float16)a.x; f.v[1]=(_Float16)a.y; f.v[2]=(_Float16)a.z; f.v[3]=(_Float16)a.w;
        f.v[4]=(_Float16)c.x; f.v[5]=(_Float16)c.y; f.v[6]=(_Float16)c.z; f.v[7]=(_Float16)c.w;
        ((uint4*)K16b)[e8] = f.u4;
    }
    #pragma unroll
    for (int i = 0; i < 4; ++i) {
        int fi = tid + 256 * i;
        int r = fi >> 4, c4 = (fi & 15) << 2;
        float4 v = *(const float4*)(Vb + (size_t)r * D + c4);
        float2* p = (float2*)&tl[r * 66 + c4];
        p[0] = make_float2(v.x, v.y);
        p[1] = make_float2(v.z, v.w);
    }
    __syncthreads();
    _Float16* VTb = VT + (size_t)b * D * S;
    #pragma unroll
    for (int i = 0; i < 2; ++i) {
        int fi = tid + 256 * i;
        int d = fi >> 3, s8 = (fi & 7) << 3;
        Frag f;
        #pragma unroll
        for (int j = 0; j < 8; ++j) f.v[j] = (_Float16)tl[(s8 + j) * 66 + d];
        *(uint4*)(VTb + (size_t)d * S + s0 + s8) = f.u4;
    }
}

// ---- main flash-attention kernel ----
// R5 inner loop (S^T = K @ Q^T operand swap, in-lane softmax, b64 P writes) +
// double-buffered kt/vt with register prefetch: ONE barrier per tile, global
// latency hidden behind compute (no vmcnt drain at the barrier).
__global__ __launch_bounds__(256, 3)
void fattn_kernel(const float* __restrict__ Q, const _Float16* __restrict__ K16,
                  const _Float16* __restrict__ VT16, float* __restrict__ Out) {
    __shared__ __align__(16) _Float16 kt[2][64 * LTS];    // K tiles  [key][d], double-buffered
    __shared__ __align__(16) _Float16 vt[2][64 * LTS];    // V^T tiles [d][key], double-buffered
    __shared__ __align__(16) _Float16 pt[4 * 16 * LTS];   // per-wave P [q 16][key 64]

    const int tid  = threadIdx.x;
    const int wave = tid >> 6;
    const int lane = tid & 63;
    const int ln   = lane & 15;
    const int quad = lane >> 4;

    const int bx = blockIdx.x;
    const int b  = bx & 15;
    const int qt = 63 - (bx >> 4);            // largest-work blocks first (LPT)

    const float* Qb = Q + (size_t)b * S * D;
    const _Float16* Kb = K16 + (size_t)b * S * D;
    const _Float16* VTb = VT16 + (size_t)b * D * S;
    float* Ob = Out + (size_t)b * S * D;

    const float qscale = 0.125f * 1.44269504088896340736f;  // 1/sqrt(64) * log2(e)
    const int qrow_base = qt * 64 + wave * 16;

    // staging geometry: thread handles fi = tid + 256*i (i=0,1): row fi>>3, 8-half chunk fi&7
    const int sr0 = tid >> 3;                 // rows 0..31   (i=0)
    const int sc8 = (tid & 7) << 3;           // half offset 0..56
    // rows 32..63 are sr0+32 (i=1)

    // Q fragments: serve as MFMA *B* operand (n=q=ln, k=d=quad*8+j)
    Frag qf[2];
    {
        const float* qrow = Qb + (size_t)(qrow_base + ln) * D + quad * 8;
        #pragma unroll
        for (int ks = 0; ks < 2; ++ks) {
            float4 a = *(const float4*)(qrow + ks * 32);
            float4 c = *(const float4*)(qrow + ks * 32 + 4);
            Frag f;
            f.v[0]=(_Float16)(a.x*qscale); f.v[1]=(_Float16)(a.y*qscale);
            f.v[2]=(_Float16)(a.z*qscale); f.v[3]=(_Float16)(a.w*qscale);
            f.v[4]=(_Float16)(c.x*qscale); f.v[5]=(_Float16)(c.y*qscale);
            f.v[6]=(_Float16)(c.z*qscale); f.v[7]=(_Float16)(c.w*qscale);
            qf[ks] = f;
        }
    }

    f32x4 o[4] = {};            // O accumulator, C-layout
    float l_acc = 0.f;          // lane-partial softmax denom for q = ln
    _Float16* ptw = pt + wave * 16 * LTS;

    // ---- preload tile 0 into buffer 0 ----
    uint4 kk[2], vv[2];
    #pragma unroll
    for (int i = 0; i < 2; ++i) {
        int r = sr0 + 32 * i;
        kk[i] = *(const uint4*)(Kb + (size_t)r * D + sc8);
        vv[i] = *(const uint4*)(VTb + (size_t)r * S + sc8);
    }
    #pragma unroll
    for (int i = 0; i < 2; ++i) {
        int r = sr0 + 32 * i;
        *(uint4*)(kt[0] + r * LTS + sc8) = kk[i];
        *(uint4*)(vt[0] + r * LTS + sc8) = vv[i];
    }

    for (int t = 0; t <= qt; ++t) {
        const int k0 = t * 64;
        __syncthreads();   // drains just-issued staging writes; orders buffer reuse

        const _Float16* ktc = kt[t & 1];
        const _Float16* vtc = vt[t & 1];

        // ---- issue global prefetch for tile t+1 (in flight during compute) ----
        const bool pre = (t < qt);
        if (pre) {
            const int k0n = k0 + 64;
            #pragma unroll
            for (int i = 0; i < 2; ++i) {
                int r = sr0 + 32 * i;
                kk[i] = *(const uint4*)(Kb + (size_t)(k0n + r) * D + sc8);
                vv[i] = *(const uint4*)(VTb + (size_t)r * S + k0n + sc8);
            }
        }

        // ---- S^T = K @ Q^T, per 16-key group ct ----
        #pragma unroll
        for (int ct = 0; ct < 4; ++ct) {
            Frag kf0, kf1;   // A-operand: m=key=ct*16+ln, k=d
            kf0.u4 = *(const uint4*)(ktc + (ct * 16 + ln) * LTS + quad * 8);
            kf1.u4 = *(const uint4*)(ktc + (ct * 16 + ln) * LTS + 32 + quad * 8);
            f32x4 acc = {0.f, 0.f, 0.f, 0.f};
            acc = __builtin_amdgcn_mfma_f32_16x16x32_f16(kf0.v, qf[0].v, acc, 0, 0, 0);
            acc = __builtin_amdgcn_mfma_f32_16x16x32_f16(kf1.v, qf[1].v, acc, 0, 0, 0);
            // lane holds keys k0+ct*16+quad*4+{0..3} for q = qrow_base+ln
            if (t == qt) {
                int keyb = k0 + ct * 16 + quad * 4;
                int qrow = qrow_base + ln;
                #pragma unroll
                for (int r = 0; r < 4; ++r)
                    if (keyb + r > qrow) acc[r] = -1e30f;
            }
            Pack4 pk;
            float psum = 0.f;
            #pragma unroll
            for (int r = 0; r < 4; ++r) {
                float p = exp2f(acc[r]);   // no-max softmax: exact by shift-invariance
                psum += p;
                pk.h[r] = (_Float16)p;
            }
            l_acc += psum;
            // b64 write, key-consecutive: P[q=ln][key]
            *(uint2*)(ptw + ln * LTS + ct * 16 + quad * 4) = pk.u;
        }

        // ---- P A-frags (m=q, k=key); same-wave RAW, no barrier needed ----
        Frag pf[2];
        #pragma unroll
        for (int ks = 0; ks < 2; ++ks)
            pf[ks].u4 = *(const uint4*)(ptw + ln * LTS + ks * 32 + quad * 8);

        // ---- O += P @ V (B from V^T: k=key contiguous) ----
        #pragma unroll
        for (int ks = 0; ks < 2; ++ks) {
            #pragma unroll
            for (int sub = 0; sub < 4; ++sub) {
                Frag vf;
                vf.u4 = *(const uint4*)(vtc + (sub * 16 + ln) * LTS + ks * 32 + quad * 8);
                o[sub] = __builtin_amdgcn_mfma_f32_16x16x32_f16(pf[ks].v, vf.v, o[sub], 0, 0, 0);
            }
        }

        // ---- stage prefetched tile t+1 into the other buffer ----
        if (pre) {
            _Float16* ktn = kt[(t + 1) & 1];
            _Float16* vtn = vt[(t + 1) & 1];
            #pragma unroll
            for (int i = 0; i < 2; ++i) {
                int r = sr0 + 32 * i;
                *(uint4*)(ktn + r * LTS + sc8) = kk[i];
                *(uint4*)(vtn + r * LTS + sc8) = vv[i];
            }
        }
    }

    // ---- epilogue: full denom per q, then normalize C-layout rows ----
    float lf = l_acc;                  // partial for q = ln, summed across quads
    lf += __shfl_xor(lf, 16, 64);
    lf += __shfl_xor(lf, 32, 64);      // full denom at every quad for q = ln
    #pragma unroll
    for (int r = 0; r < 4; ++r) {
        float lrow = __shfl(lf, quad * 4 + r, 64);   // denom for O row quad*4+r
        float inv = 1.0f / lrow;
        #pragma unroll
        for (int sub = 0; sub < 4; ++sub) {
            Ob[(size_t)(qrow_base + quad * 4 + r) * D + sub * 16 + ln] =
                o[sub][r] * inv;
        }
    }
}

extern "C" void kernel_launch(void* const* d_in, const int* in_sizes, int n_in,
                              void* d_out, int out_size, void* d_ws, size_t ws_size,
                              hipStream_t stream) {
    const float* Q = (const float*)d_in[0];
    const float* K = (const float*)d_in[1];
    const float* V = (const float*)d_in[2];
    float* O = (float*)d_out;

    _Float16* K16 = (_Float16*)d_ws;                                    // 8.4 MB
    _Float16* VT16 = (_Float16*)((char*)d_ws + (size_t)NB * S * D * 2); // 8.4 MB

    hipLaunchKernelGGL(prep_kernel, dim3(S / 64, NB), dim3(256), 0, stream, K, V, K16, VT16);
    hipLaunchKernelGGL(fattn_kernel, dim3(64 * NB), dim3(256), 0, stream, Q, K16, VT16, O);
}

// Round 7
// 201.741 us; speedup vs baseline: 1.2187x; 1.2187x over previous
//
#include <hip/hip_runtime.h>

typedef _Float16 half8 __attribute__((ext_vector_type(8)));
typedef float f32x4 __attribute__((ext_vector_type(4)));

union Frag { half8 v; unsigned int u32[4]; uint4 u4; };
union Pack4 { _Float16 h[4]; uint2 u; };

constexpr int S = 4096;
constexpr int D = 64;
constexpr int NB = 16;
constexpr int LTS = 72;   // f16 LDS row stride (dword stride 36): min-phase b128 frag reads + b64 P writes

// ---- fused prepass: K f32 -> f16 row-major; V f32 -> f16 transposed [b][d][s] ----
__global__ __launch_bounds__(256)
void prep_kernel(const float* __restrict__ K, const float* __restrict__ V,
                 _Float16* __restrict__ K16, _Float16* __restrict__ VT) {
    __shared__ float tl[64 * 66];
    const int tid = threadIdx.x;
    const int s0 = blockIdx.x * 64;
    const int b  = blockIdx.y;
    const float* Kb = K + ((size_t)b * S + s0) * D;
    const float* Vb = V + ((size_t)b * S + s0) * D;
    _Float16* K16b = K16 + ((size_t)b * S + s0) * D;

    #pragma unroll
    for (int i = 0; i < 2; ++i) {
        int e8 = tid + 256 * i;
        float4 a = ((const float4*)Kb)[2 * e8];
        float4 c = ((const float4*)Kb)[2 * e8 + 1];
        Frag f;
        f.v[0]=(_Float16)a.x; f.v[1]=(_Float16)a.y; f.v[2]=(_Float16)a.z; f.v[3]=(_Float16)a.w;
        f.v[4]=(_Float16)c.x; f.v[5]=(_Float16)c.y; f.v[6]=(_Float16)c.z; f.v[7]=(_Float16)c.w;
        ((uint4*)K16b)[e8] = f.u4;
    }
    #pragma unroll
    for (int i = 0; i < 4; ++i) {
        int fi = tid + 256 * i;
        int r = fi >> 4, c4 = (fi & 15) << 2;
        float4 v = *(const float4*)(Vb + (size_t)r * D + c4);
        float2* p = (float2*)&tl[r * 66 + c4];
        p[0] = make_float2(v.x, v.y);
        p[1] = make_float2(v.z, v.w);
    }
    __syncthreads();
    _Float16* VTb = VT + (size_t)b * D * S;
    #pragma unroll
    for (int i = 0; i < 2; ++i) {
        int fi = tid + 256 * i;
        int d = fi >> 3, s8 = (fi & 7) << 3;
        Frag f;
        #pragma unroll
        for (int j = 0; j < 8; ++j) f.v[j] = (_Float16)tl[(s8 + j) * 66 + d];
        *(uint4*)(VTb + (size_t)d * S + s0 + s8) = f.u4;
    }
}

// ================= R5 hot loop, parameterized over key-tile range ==============
// S^T = K @ Q^T operand swap, in-lane no-max softmax, b64 P writes.
// SPLIT=1: writes unnormalized O-partial + l-partial to workspace.
// SPLIT=0: full range, normalizes and writes Out directly (exact R5 fallback).
template <int SPLIT>
__device__ __forceinline__
void fattn_body(const float* __restrict__ Q, const _Float16* __restrict__ K16,
                const _Float16* __restrict__ VT16, float* __restrict__ Out,
                float* __restrict__ OP, float* __restrict__ LP,
                int b, int qt, int t0, int t1, int h) {
    __shared__ __align__(16) _Float16 kt[64 * LTS];
    __shared__ __align__(16) _Float16 vt[64 * LTS];
    __shared__ __align__(16) _Float16 pt[4 * 16 * LTS];

    const int tid  = threadIdx.x;
    const int wave = tid >> 6;
    const int lane = tid & 63;
    const int ln   = lane & 15;
    const int quad = lane >> 4;

    const float* Qb = Q + (size_t)b * S * D;
    const _Float16* Kb = K16 + (size_t)b * S * D;
    const _Float16* VTb = VT16 + (size_t)b * D * S;

    const float qscale = 0.125f * 1.44269504088896340736f;  // 1/sqrt(64) * log2(e)
    const int qrow_base = qt * 64 + wave * 16;

    // Q fragments: serve as MFMA *B* operand (n=q=ln, k=d=quad*8+j)
    Frag qf[2];
    {
        const float* qrow = Qb + (size_t)(qrow_base + ln) * D + quad * 8;
        #pragma unroll
        for (int ks = 0; ks < 2; ++ks) {
            float4 a = *(const float4*)(qrow + ks * 32);
            float4 c = *(const float4*)(qrow + ks * 32 + 4);
            Frag f;
            f.v[0]=(_Float16)(a.x*qscale); f.v[1]=(_Float16)(a.y*qscale);
            f.v[2]=(_Float16)(a.z*qscale); f.v[3]=(_Float16)(a.w*qscale);
            f.v[4]=(_Float16)(c.x*qscale); f.v[5]=(_Float16)(c.y*qscale);
            f.v[6]=(_Float16)(c.z*qscale); f.v[7]=(_Float16)(c.w*qscale);
            qf[ks] = f;
        }
    }

    f32x4 o[4] = {};
    float l_acc = 0.f;
    _Float16* ptw = pt + wave * 16 * LTS;

    for (int t = t0; t < t1; ++t) {
        const int k0 = t * 64;
        __syncthreads();

        #pragma unroll
        for (int i = 0; i < 2; ++i) {
            int fi = tid + 256 * i;
            int r = fi >> 3, c8 = (fi & 7) << 3;
            uint4 kk = *(const uint4*)(Kb + (size_t)(k0 + r) * D + c8);
            uint4 vv = *(const uint4*)(VTb + (size_t)r * S + k0 + c8);
            *(uint4*)(kt + r * LTS + c8) = kk;
            *(uint4*)(vt + r * LTS + c8) = vv;
        }
        __syncthreads();

        #pragma unroll
        for (int ct = 0; ct < 4; ++ct) {
            Frag kf0, kf1;
            kf0.u4 = *(const uint4*)(kt + (ct * 16 + ln) * LTS + quad * 8);
            kf1.u4 = *(const uint4*)(kt + (ct * 16 + ln) * LTS + 32 + quad * 8);
            f32x4 acc = {0.f, 0.f, 0.f, 0.f};
            acc = __builtin_amdgcn_mfma_f32_16x16x32_f16(kf0.v, qf[0].v, acc, 0, 0, 0);
            acc = __builtin_amdgcn_mfma_f32_16x16x32_f16(kf1.v, qf[1].v, acc, 0, 0, 0);
            if (t == qt) {   // only the diagonal tile needs masking
                int keyb = k0 + ct * 16 + quad * 4;
                int qrow = qrow_base + ln;
                #pragma unroll
                for (int r = 0; r < 4; ++r)
                    if (keyb + r > qrow) acc[r] = -1e30f;
            }
            Pack4 pk;
            float psum = 0.f;
            #pragma unroll
            for (int r = 0; r < 4; ++r) {
                float p = exp2f(acc[r]);   // no-max softmax: exact by shift-invariance
                psum += p;
                pk.h[r] = (_Float16)p;
            }
            l_acc += psum;
            *(uint2*)(ptw + ln * LTS + ct * 16 + quad * 4) = pk.u;
        }

        Frag pf[2];
        #pragma unroll
        for (int ks = 0; ks < 2; ++ks)
            pf[ks].u4 = *(const uint4*)(ptw + ln * LTS + ks * 32 + quad * 8);

        #pragma unroll
        for (int ks = 0; ks < 2; ++ks) {
            #pragma unroll
            for (int sub = 0; sub < 4; ++sub) {
                Frag vf;
                vf.u4 = *(const uint4*)(vt + (sub * 16 + ln) * LTS + ks * 32 + quad * 8);
                o[sub] = __builtin_amdgcn_mfma_f32_16x16x32_f16(pf[ks].v, vf.v, o[sub], 0, 0, 0);
            }
        }
    }

    // full denom for q=ln at every lane (sum the 4 quad-partials)
    float lf = l_acc;
    lf += __shfl_xor(lf, 16, 64);
    lf += __shfl_xor(lf, 32, 64);

    if (SPLIT) {
        float* OPb = OP + ((size_t)(b * 64 + qt) * 2 + h) * 4096;
        float* LPb = LP + ((size_t)(b * 64 + qt) * 2 + h) * 64;
        #pragma unroll
        for (int r = 0; r < 4; ++r) {
            #pragma unroll
            for (int sub = 0; sub < 4; ++sub)
                OPb[(wave * 16 + quad * 4 + r) * 64 + sub * 16 + ln] = o[sub][r];
        }
        if (quad == 0) LPb[wave * 16 + ln] = lf;   // lanes 0..15 hold q=ln
    } else {
        float* Ob = Out + (size_t)b * S * D;
        #pragma unroll
        for (int r = 0; r < 4; ++r) {
            float lrow = __shfl(lf, quad * 4 + r, 64);
            float inv = 1.0f / lrow;
            #pragma unroll
            for (int sub = 0; sub < 4; ++sub)
                Ob[(size_t)(qrow_base + quad * 4 + r) * D + sub * 16 + ln] =
                    o[sub][r] * inv;
        }
    }
}

// split-K x2: grid 2048 = 64 qt x 2 halves x 16 batches, LPT (qt descending)
__global__ __launch_bounds__(256, 5)
void fattn_split_kernel(const float* __restrict__ Q, const _Float16* __restrict__ K16,
                        const _Float16* __restrict__ VT16,
                        float* __restrict__ OP, float* __restrict__ LP) {
    const int bx = blockIdx.x;
    const int qt = 63 - (bx >> 5);
    const int h  = (bx >> 4) & 1;
    const int b  = bx & 15;
    const int n  = qt + 1;
    const int n0 = (n + 1) >> 1;          // h0 gets ceil(n/2) tiles
    const int t0 = h ? n0 : 0;
    const int t1 = h ? n  : n0;
    fattn_body<1>(Q, K16, VT16, nullptr, OP, LP, b, qt, t0, t1, h);
}

// exact R5 fallback (used when workspace is too small for split partials)
__global__ __launch_bounds__(256, 5)
void fattn_kernel(const float* __restrict__ Q, const _Float16* __restrict__ K16,
                  const _Float16* __restrict__ VT16, float* __restrict__ Out) {
    const int bx = blockIdx.x;
    const int b  = bx & 15;
    const int qt = 63 - (bx >> 4);
    fattn_body<0>(Q, K16, VT16, Out, nullptr, nullptr, b, qt, 0, qt + 1, 0);
}

// merge: Out = (P0 + P1) / (l0 + l1); one block per (b, qt)
__global__ __launch_bounds__(256)
void reduce_kernel(const float* __restrict__ OP, const float* __restrict__ LP,
                   float* __restrict__ Out) {
    const int rb = blockIdx.x;
    const int b  = rb & 15;
    const int qt = rb >> 4;
    const int tid = threadIdx.x;
    const float* p0 = OP + (size_t)(b * 64 + qt) * 2 * 4096;
    const float* p1 = p0 + 4096;
    const float* l0 = LP + (size_t)(b * 64 + qt) * 2 * 64;
    const float* l1 = l0 + 64;
    float* Ob = Out + (size_t)b * S * D + (size_t)qt * 4096;
    #pragma unroll
    for (int i = 0; i < 4; ++i) {
        int e4 = tid + 256 * i;                 // float4 index within 4096 floats
        float4 a = ((const float4*)p0)[e4];
        float4 c = ((const float4*)p1)[e4];
        int q = e4 >> 4;
        float inv = 1.0f / (l0[q] + l1[q]);
        float4 r;
        r.x = (a.x + c.x) * inv;
        r.y = (a.y + c.y) * inv;
        r.z = (a.z + c.z) * inv;
        r.w = (a.w + c.w) * inv;
        ((float4*)Ob)[e4] = r;
    }
}

extern "C" void kernel_launch(void* const* d_in, const int* in_sizes, int n_in,
                              void* d_out, int out_size, void* d_ws, size_t ws_size,
                              hipStream_t stream) {
    const float* Q = (const float*)d_in[0];
    const float* K = (const float*)d_in[1];
    const float* V = (const float*)d_in[2];
    float* O = (float*)d_out;

    const size_t prepBytes = (size_t)NB * S * D * 2;        // 8.39 MB each
    _Float16* K16  = (_Float16*)d_ws;
    _Float16* VT16 = (_Float16*)((char*)d_ws + prepBytes);

    const size_t opOff = 2 * prepBytes;                     // 16.78 MB
    const size_t opBytes = (size_t)NB * 64 * 2 * 4096 * 4;  // 33.55 MB
    const size_t lpOff = opOff + opBytes;
    const size_t lpBytes = (size_t)NB * 64 * 2 * 64 * 4;    // 0.52 MB
    const size_t need = lpOff + lpBytes;                    // ~50.9 MB

    hipLaunchKernelGGL(prep_kernel, dim3(S / 64, NB), dim3(256), 0, stream, K, V, K16, VT16);

    if (ws_size >= need) {
        float* OP = (float*)((char*)d_ws + opOff);
        float* LP = (float*)((char*)d_ws + lpOff);
        hipLaunchKernelGGL(fattn_split_kernel, dim3(128 * NB), dim3(256), 0, stream,
                           Q, K16, VT16, OP, LP);
        hipLaunchKernelGGL(reduce_kernel, dim3(64 * NB), dim3(256), 0, stream, OP, LP, O);
    } else {
        hipLaunchKernelGGL(fattn_kernel, dim3(64 * NB), dim3(256), 0, stream, Q, K16, VT16, O);
    }
}